// Round 6
// baseline (85.890 us; speedup 1.0000x reference)
//
#include <hip/hip_runtime.h>
#include <hip/hip_bf16.h>

// ---------------------------------------------------------------------------
// ParticleQAEEncoder.
// Jet (n=10, 1024 amps, depth 4): ONE wave per event, 16 cplx amps/lane.
//   latent wires 0..5 -> lane bits 5..0; trash wires 6..9 -> reg bits 3..0.
// Round-6: round-3 PROVEN structure for everything touching cross-lane ops
// (scalar float state arrays sre/sim_, scalar DPP/swizzle/bperm, scalar
// shfl epilogue). Rounds 4/5 failed only where f2 vectors met cross-lane
// codegen; sim4 proved f2 pure-arithmetic is safe. So f2 is used ONLY in:
//   * encoding factors + product tree (pure cmul chains)
//   * reg-wire RYs (pack/compute/unpack; pk-FMA operands never come from DPP)
// Final-depth P2 eliminated: flipping all 4 trash (reg) bits negates every
// Z sign mask, so it folds into negating the per-lane z-partials when pl=1.
// DS ops/depth: P1=16, mask32=32, mask16=32 -> 80. No LDS, no barriers.
// ---------------------------------------------------------------------------

typedef float f2 __attribute__((ext_vector_type(2)));

struct cplx { float re, im; };

__device__ __forceinline__ f2 cmul(f2 a, f2 b) {
  f2 r; r.x = a.x*b.x - a.y*b.y; r.y = a.x*b.y + a.y*b.x; return r;
}
__device__ __forceinline__ f2 csel(int c, f2 a, f2 b) {
  f2 r; r.x = c ? a.x : b.x; r.y = c ? a.y : b.y; return r;
}

// ---- cross-lane helpers (scalar float ONLY — round-3 proven) ----
template<int CTRL, int ROW, int BANK, bool BC>
__device__ __forceinline__ float dppf(float oldv, float v) {
  return __int_as_float(__builtin_amdgcn_update_dpp(
      __float_as_int(oldv), __float_as_int(v), CTRL, ROW, BANK, BC));
}
__device__ __forceinline__ float xor1f(float v) { return dppf<0xB1, 0xF, 0xF, true>(v, v); }   // quad_perm [1,0,3,2]
__device__ __forceinline__ float xor2f(float v) { return dppf<0x4E, 0xF, 0xF, true>(v, v); }   // quad_perm [2,3,0,1]
__device__ __forceinline__ float xor8f(float v) { return dppf<0x128, 0xF, 0xF, true>(v, v); }  // row_ror:8
__device__ __forceinline__ float xor4f(float v) {
  float t = dppf<0x104, 0xF, 0xA, false>(v, v);   // row_shl:4 -> banks 1,3
  return    dppf<0x114, 0xF, 0x5, false>(t, v);   // row_shr:4 -> banks 0,2
}
__device__ __forceinline__ float xor16f(float v) {
  return __int_as_float(__builtin_amdgcn_ds_swizzle(__float_as_int(v), 0x401F));
}
__device__ __forceinline__ float bpermf(int addr, float v) {
  return __int_as_float(__builtin_amdgcn_ds_bpermute(addr, __float_as_int(v)));
}

// |0>-column of RZ(phi)*RY(pt)*RX(eta)  (applied RX,RY,RZ order) — f2, pure
__device__ __forceinline__ void enc_col(float pt, float eta, float phi,
                                        f2* A, f2* Bq) {
  float cx = __cosf(0.5f*eta), sx = __sinf(0.5f*eta);
  float cy = __cosf(0.5f*pt),  sy = __sinf(0.5f*pt);
  float cz = __cosf(0.5f*phi), sz = __sinf(0.5f*phi);
  float u = cy*cx, v = sy*sx;
  float p = sy*cx, q = -cy*sx;
  A->x  = cz*u + sz*v;  A->y  = cz*v - sz*u;
  Bq->x = cz*p - sz*q;  Bq->y = cz*q + sz*p;
}

// ---------------- jet: one wave per event ----------------
__device__ void jet_sim(const float* __restrict__ xr, const float* __restrict__ jw,
                        float* __restrict__ out, int b, int lane, int B) {
  f2 A[10], Bw[10];
  #pragma unroll
  for (int k = 0; k < 10; ++k)
    enc_col(xr[26+k], xr[36+k], xr[46+k], &A[k], &Bw[k]);

  // lane factor over wires 0..5 (lane bit 5-w) — f2 pure arithmetic
  f2 f = csel((lane>>5)&1, Bw[0], A[0]);
  f = cmul(f, csel((lane>>4)&1, Bw[1], A[1]));
  f = cmul(f, csel((lane>>3)&1, Bw[2], A[2]));
  f = cmul(f, csel((lane>>2)&1, Bw[3], A[3]));
  f = cmul(f, csel((lane>>1)&1, Bw[4], A[4]));
  f = cmul(f, csel( lane    &1, Bw[5], A[5]));

  // product tree over reg bits (f2), unpacked into scalar state arrays
  float sre[16], sim_[16];
  {
    f2 h6[2]; h6[0] = cmul(f, A[6]); h6[1] = cmul(f, Bw[6]);
    f2 h7[4];
    #pragma unroll
    for (int j = 0; j < 2; ++j) { h7[2*j] = cmul(h6[j], A[7]); h7[2*j+1] = cmul(h6[j], Bw[7]); }
    f2 h8[8];
    #pragma unroll
    for (int j = 0; j < 4; ++j) { h8[2*j] = cmul(h7[j], A[8]); h8[2*j+1] = cmul(h7[j], Bw[8]); }
    #pragma unroll
    for (int j = 0; j < 8; ++j) {
      f2 e0 = cmul(h8[j], A[9]);  sre[2*j]   = e0.x; sim_[2*j]   = e0.y;
      f2 e1 = cmul(h8[j], Bw[9]); sre[2*j+1] = e1.x; sim_[2*j+1] = e1.y;
    }
  }

  const int a63 = (lane ^ 63) << 2;       // bpermute byte addr for xor63
  const int a32 = (lane ^ 32) << 2;       // bpermute byte addr for xor32
  const int pl  = __popc(lane) & 1;       // parity of latent (all lane bits)

  #pragma unroll
  for (int d = 0; d < 4; ++d) {
    float c[10], s[10];
    #pragma unroll
    for (int k = 0; k < 10; ++k) __sincosf(0.5f * jw[d*10 + k], &s[k], &c[k]);

    // P1: flip all latent (lane^63) iff parity(trash)=parity(r) (compile-time)
    #pragma unroll
    for (int r = 0; r < 16; ++r) {
      if (__popc(r) & 1) {
        sre[r] = bpermf(a63, sre[r]);
        sim_[r] = bpermf(a63, sim_[r]);
      }
    }

    // RY on lane wires 0..5 (masks 32,16,8,4,2,1) — scalar, round-3 proven
#define LANE_RY(K, M, SHUF)                                   \
    { const float cc = c[K];                                  \
      const float sg = (lane & (M)) ? s[K] : -s[K];           \
      _Pragma("unroll")                                       \
      for (int r = 0; r < 16; ++r) {                          \
        float ore = SHUF(sre[r]), oim = SHUF(sim_[r]);        \
        sre[r]  = cc*sre[r]  + sg*ore;                        \
        sim_[r] = cc*sim_[r] + sg*oim;                        \
      } }
#define SH32(v) bpermf(a32, v)
    LANE_RY(0, 32, SH32)
    LANE_RY(1, 16, xor16f)
    LANE_RY(2,  8, xor8f)
    LANE_RY(3,  4, xor4f)
    LANE_RY(4,  2, xor2f)
    LANE_RY(5,  1, xor1f)
#undef SH32
#undef LANE_RY

    // RY on reg wires 6..9 (trash; reg bit 9-k) — f2 pack/compute/unpack
    // (pk-FMA operands come from plain VGPRs, never from DPP results)
    #pragma unroll
    for (int k = 6; k < 10; ++k) {
      const int mr = 1 << (9-k);
      const float cc = c[k], sk = s[k];
      #pragma unroll
      for (int r = 0; r < 16; ++r) {
        if (!(r & mr)) {
          f2 a; a.x = sre[r];    a.y = sim_[r];
          f2 bb; bb.x = sre[r|mr]; bb.y = sim_[r|mr];
          f2 na = cc*a - sk*bb;
          f2 nb = sk*a + cc*bb;
          sre[r]    = na.x; sim_[r]    = na.y;
          sre[r|mr] = nb.x; sim_[r|mr] = nb.y;
        }
      }
    }

    // P2: flip trash (reg bits, r^15) iff pl — explicit swap, depths 0..2.
    // Depth 3's P2 is folded into the epilogue sign flip (flipping all 4
    // trash bits negates every Z sign mask).
    if (d < 3) {
      #pragma unroll
      for (int r = 0; r < 8; ++r) {
        float ar = sre[r], ai = sim_[r], br = sre[r^15], bi = sim_[r^15];
        sre[r]    = pl ? br : ar;  sim_[r]    = pl ? bi : ai;
        sre[r^15] = pl ? ar : br;  sim_[r^15] = pl ? ai : bi;
      }
    }
  }

  // <Z> on trash wires 6..9 = reg bits 3..0 (pre-P2 state; pl-negate below)
  float p[16];
  #pragma unroll
  for (int r = 0; r < 16; ++r) p[r] = sre[r]*sre[r] + sim_[r]*sim_[r];
  float z0 = 0.f, z1 = 0.f, z2 = 0.f, z3 = 0.f;
  #pragma unroll
  for (int r = 0; r < 16; ++r) {
    z0 += (r & 8) ? -p[r] : p[r];
    z1 += (r & 4) ? -p[r] : p[r];
    z2 += (r & 2) ? -p[r] : p[r];
    z3 += (r & 1) ? -p[r] : p[r];
  }
  const float sgn = pl ? -1.0f : 1.0f;   // folded depth-3 P2
  z0 *= sgn; z1 *= sgn; z2 *= sgn; z3 *= sgn;
  // round-3 proven shfl reduction
  #pragma unroll
  for (int j = 1; j <= 32; j <<= 1) {
    z0 += __shfl_xor(z0, j, 64);
    z1 += __shfl_xor(z1, j, 64);
    z2 += __shfl_xor(z2, j, 64);
    z3 += __shfl_xor(z3, j, 64);
  }
  if (lane == 0) {
    float* o = out + (size_t)5*B + (size_t)b*4;
    o[0] = z0; o[1] = z1; o[2] = z2; o[3] = z3;
  }
}

// ---------------- ele/mu: n=4, 16 amps per thread, depth 1 (f2, HW-proven) --
__device__ void sim4(const float* __restrict__ pt, const float* __restrict__ eta,
                     const float* __restrict__ phi, const float* __restrict__ w,
                     float* z_w2, float* z_w3) {
  f2 A[4], Bw[4];
  #pragma unroll
  for (int k = 0; k < 4; ++k)
    enc_col(pt[k], eta[k], phi[k], &A[k], &Bw[k]);

  f2 st[16];
  #pragma unroll
  for (int i = 0; i < 16; ++i) {
    f2 f = csel((i>>3)&1, Bw[0], A[0]);
    f = cmul(f, csel((i>>2)&1, Bw[1], A[1]));
    f = cmul(f, csel((i>>1)&1, Bw[2], A[2]));
    f = cmul(f, csel( i    &1, Bw[3], A[3]));
    st[i] = f;
  }
  f2 t;
  t = st[1]; st[1] = st[13]; st[13] = t;
  t = st[2]; st[2] = st[14]; st[14] = t;
  t = st[5]; st[5] = st[9];  st[9]  = t;
  t = st[6]; st[6] = st[10]; st[10] = t;
  #pragma unroll
  for (int k = 0; k < 4; ++k) {
    float a5 = 0.5f * w[k];
    float c = __cosf(a5), s = __sinf(a5);
    const int m = 8 >> k;
    #pragma unroll
    for (int i = 0; i < 16; ++i) {
      if (!(i & m)) {
        f2 a = st[i], bb = st[i|m];
        st[i]   = c*a - s*bb;
        st[i|m] = s*a + c*bb;
      }
    }
  }
  t = st[4]; st[4] = st[7];  st[7]  = t;
  t = st[5]; st[5] = st[6];  st[6]  = t;
  t = st[8]; st[8] = st[11]; st[11] = t;
  t = st[9]; st[9] = st[10]; st[10] = t;

  float z2 = 0.f, z3 = 0.f;
  #pragma unroll
  for (int i = 0; i < 16; ++i) {
    f2 q = st[i]*st[i];
    float p = q.x + q.y;
    z2 += ((i>>1)&1) ? -p : p;
    z3 += ( i    &1) ? -p : p;
  }
  *z_w2 = z2; *z_w3 = z3;
}

__global__ __launch_bounds__(256, 4)
void qae_kernel(const float* __restrict__ x,
                const float* __restrict__ met_w,
                const float* __restrict__ ele_w,
                const float* __restrict__ mu_w,
                const float* __restrict__ jet_w,
                float* __restrict__ out, int B, int jet_blocks) {
  if ((int)blockIdx.x < jet_blocks) {
    int b = blockIdx.x * 4 + (threadIdx.x >> 6);   // one wave per event
    int lane = threadIdx.x & 63;
    if (b < B)
      jet_sim(x + (size_t)b*56, jet_w, out, b, lane, B);
  } else {
    int b = ((int)blockIdx.x - jet_blocks) * 256 + threadIdx.x;
    if (b >= B) return;
    const float* xr = x + (size_t)b*56;
    // ---- met: n=1 analytic ----
    {
      float pt = xr[0], phi = xr[1], mw = met_w[0];
      float cy = __cosf(0.5f*pt),  sy = __sinf(0.5f*pt);
      float cz = __cosf(0.5f*phi), sz = __sinf(0.5f*phi);
      float cw = __cosf(0.5f*mw),  sw = __sinf(0.5f*mw);
      f2 al; al.x = cz*cy; al.y = -sz*cy;
      f2 be; be.x = cz*sy; be.y =  sz*sy;
      f2 a0 = cw*al - sw*be;
      f2 a1 = sw*al + cw*be;
      out[b] = (a0.x*a0.x + a0.y*a0.y) - (a1.x*a1.x + a1.y*a1.y);
    }
    float z2, z3;
    sim4(xr+2,  xr+6,  xr+10, ele_w, &z2, &z3);
    out[B   + b*2 + 0] = z2;  out[B   + b*2 + 1] = z3;
    sim4(xr+14, xr+18, xr+22, mu_w, &z2, &z3);
    out[3*B + b*2 + 0] = z2;  out[3*B + b*2 + 1] = z3;
  }
}

extern "C" void kernel_launch(void* const* d_in, const int* in_sizes, int n_in,
                              void* d_out, int out_size, void* d_ws, size_t ws_size,
                              hipStream_t stream) {
  const float* x     = (const float*)d_in[0];
  const float* met_w = (const float*)d_in[1];
  const float* ele_w = (const float*)d_in[2];
  const float* mu_w  = (const float*)d_in[3];
  const float* jet_w = (const float*)d_in[4];
  float* out = (float*)d_out;
  int B = in_sizes[0] / 56;
  int jet_blocks   = (B + 3) / 4;            // one wave (64 lanes) per event
  int small_blocks = (B + 255) / 256;        // one thread per event
  qae_kernel<<<dim3(jet_blocks + small_blocks), dim3(256), 0, stream>>>(
      x, met_w, ele_w, mu_w, jet_w, out, B, jet_blocks);
}